// Round 5
// baseline (167.267 us; speedup 1.0000x reference)
//
#include <hip/hip_runtime.h>

typedef __attribute__((ext_vector_type(4))) float f32x4;
typedef __attribute__((ext_vector_type(8))) __bf16 bf16x8;
typedef __attribute__((ext_vector_type(4))) unsigned short us4;
typedef __attribute__((ext_vector_type(8))) unsigned short us8;

#define B_  16
#define C_  512
#define N_  1024
#define G_  32
#define GS  16

__device__ inline unsigned short f2bf(float f) {
  unsigned u = __builtin_bit_cast(unsigned, f);
  u += 0x7fffu + ((u >> 16) & 1u);
  return (unsigned short)(u >> 16);
}

#define GLOAD_LDS16(gp, lp) __builtin_amdgcn_global_load_lds( \
    (const __attribute__((address_space(1))) unsigned int*)(gp), \
    (__attribute__((address_space(3))) unsigned int*)(lp), 16, 0, 0)

// ---------------- GroupNorm stats + weight conversion (folded) ----------------
__global__ __launch_bounds__(256) void gn_statsW(const float* __restrict__ x,
                                                 float* __restrict__ stats,
                                                 const float* __restrict__ wq, const float* __restrict__ wk,
                                                 const float* __restrict__ wv, const float* __restrict__ wo,
                                                 const float* __restrict__ bq, const float* __restrict__ bk,
                                                 unsigned short* __restrict__ wqk, unsigned short* __restrict__ wvb,
                                                 unsigned short* __restrict__ wob, float* __restrict__ bqk) {
  int bg = blockIdx.x;                       // b*32+g
  int tid = threadIdx.x;
  // folded weight conversion: block bg covers slice [bg*512, bg*512+512)
  {
    int base = bg * 512;
#pragma unroll
    for (int it = 0; it < 2; ++it) {
      int i = base + it * 256 + tid;
      wqk[i]           = f2bf(wq[i]);
      wqk[262144 + i]  = f2bf(wk[i]);
      wvb[i]           = f2bf(wv[i]);
      wob[i]           = f2bf(wo[i]);
    }
    if (bg == 0) {
#pragma unroll
      for (int it = 0; it < 2; ++it) {
        int j = it * 256 + tid;
        bqk[j]       = bq[j];
        bqk[512 + j] = bk[j];
      }
    }
  }
  const float* xp = x + (long)bg * (GS * N_);
  float s = 0.f, ss = 0.f;
  for (int i = tid * 4; i < GS * N_; i += 1024) {
    f32x4 v = *(const f32x4*)&xp[i];
    s += v.x + v.y + v.z + v.w;
    ss += v.x * v.x + v.y * v.y + v.z * v.z + v.w * v.w;
  }
  __shared__ float r1[256], r2[256];
  r1[tid] = s; r2[tid] = ss; __syncthreads();
  for (int off = 128; off > 0; off >>= 1) {
    if (tid < off) { r1[tid] += r1[tid + off]; r2[tid] += r2[tid + off]; }
    __syncthreads();
  }
  if (tid == 0) {
    float mean = r1[0] * (1.f / (GS * N_));
    float var  = r2[0] * (1.f / (GS * N_)) - mean * mean;
    stats[bg * 2]     = mean;
    stats[bg * 2 + 1] = rsqrtf(var + 1e-6f);
  }
}

// normalize + transpose: x[b,c,n] -> ht[(b*N+n)*C + c]  (bf16)
__global__ __launch_bounds__(256) void gn_apply(const float* __restrict__ x,
                                                const float* __restrict__ stats,
                                                const float* __restrict__ gamma,
                                                const float* __restrict__ beta,
                                                unsigned short* __restrict__ ht) {
  int b = blockIdx.z, ct = blockIdx.y, nt = blockIdx.x;
  int c0 = ct * 64, n0 = nt * 64;
  int tid = threadIdx.x;
  __shared__ unsigned short L[64 * 68];
  const float* xp = x + ((long)b * C_ + c0) * N_ + n0;
#pragma unroll
  for (int i = 0; i < 4; ++i) {
    int li = tid + i * 256;        // 0..1023
    int row = li >> 4;             // c offset 0..63
    int col4 = (li & 15) * 4;      // n offset
    f32x4 v = *(const f32x4*)&xp[(long)row * N_ + col4];
    int c = c0 + row;
    float mean = stats[(b * G_ + (c >> 4)) * 2];
    float rstd = stats[(b * G_ + (c >> 4)) * 2 + 1];
    float gm = gamma[c] * rstd;
    float bt = beta[c] - mean * gm;
    us4 o;
    o.x = f2bf(v.x * gm + bt); o.y = f2bf(v.y * gm + bt);
    o.z = f2bf(v.z * gm + bt); o.w = f2bf(v.w * gm + bt);
    *(us4*)&L[row * 68 + col4] = o;
  }
  __syncthreads();
#pragma unroll
  for (int i = 0; i < 2; ++i) {
    int s = tid + i * 256;         // 0..511
    int n = s >> 3;
    int cs = (s & 7) * 8;
    us8 o;
#pragma unroll
    for (int j = 0; j < 8; ++j) o[j] = L[(cs + j) * 68 + n];
    *(us8*)&ht[((long)b * N_ + n0 + n) * C_ + c0 + cs] = o;
  }
}

// ---------------- 256x(256|128) 8-wave MFMA GEMM, phased counted-vmcnt pipeline ----------------
// D[i,j] = sum_k A[i,k]*B[j,k]; both operands K-contiguous rows.
__device__ inline f32x4 mfma16(bf16x8 a, bf16x8 b, f32x4 c) {
  return __builtin_amdgcn_mfma_f32_16x16x32_bf16(a, b, c, 0, 0, 0);
}

__device__ inline int swz(int b) { return b ^ (((b >> 9) & 1) << 5); }

// EPI: 0 = +bias[col], bf16    1 = +bias[row], bf16
//      4 = +bias[row]+residual, f32 to out[z, row, col]
//      5 = exp2(v*scale) bf16 + per-row partial sums -> rs
//      6 = v * dinv(row), bf16
template<int NREP, int EPI>
__global__ __launch_bounds__(512, 2) void gemm256(
    const unsigned short* __restrict__ A, long lda, long Az,
    const unsigned short* __restrict__ Bm, long ldb, long Bz,
    void* __restrict__ Dp, long ldd, long Dz,
    const float* __restrict__ bias, float scale, int K,
    const float* __restrict__ residual, float* __restrict__ rs) {
  constexpr int BN = NREP * 64;
  const int z = blockIdx.z;
  const long row0 = (long)blockIdx.x * 256;
  const long col0 = (long)blockIdx.y * BN;
  const int tid  = threadIdx.x;
  const int lane = tid & 63;
  const int wave = tid >> 6;
  const int wm = wave >> 2;           // 0..1
  const int wn = wave & 3;            // 0..3
  const int lr = lane & 15;
  const int khb = (lane >> 4) * 16;   // byte offset of 16B chunk within 128B row

  __shared__ unsigned short Abuf[2][16384];      // [256][64] per buf (4 units of 4096 shorts)
  __shared__ unsigned short Bbuf[2][NREP * 4096];
  __shared__ float dinv_s[256];

  const unsigned short* Ab = A  + (long)z * Az;
  const unsigned short* Bb = Bm + (long)z * Bz;

  if constexpr (EPI == 6) {
    if (tid < 256) {
      const float* rp = rs + ((long)z * 1024 + row0 + tid) * 16;
      float s = 0.f;
#pragma unroll
      for (int i = 0; i < 16; ++i) s += rp[i];
      dinv_s[tid] = 1.f / s;
    }
    asm volatile("s_waitcnt lgkmcnt(0)" ::: "memory");
  }

  // staging source pointers (inverse-swizzled; swz is an involution, reads reuse it)
  const unsigned short* gA[4];
#pragma unroll
  for (int r = 0; r < 4; ++r) {
    int L = swz(r * 8192 + tid * 16);
    gA[r] = Ab + (row0 + (L >> 7)) * lda + ((L & 127) >> 1);
  }
  const unsigned short* gB[NREP];
#pragma unroll
  for (int r = 0; r < NREP; ++r) {
    int L = swz(r * 8192 + tid * 16);
    gB[r] = Bb + (col0 + (L >> 7)) * ldb + ((L & 127) >> 1);
  }

  f32x4 acc[8][NREP];
#pragma unroll
  for (int m = 0; m < 8; ++m)
#pragma unroll
    for (int n = 0; n < NREP; ++n) acc[m][n] = f32x4{0.f, 0.f, 0.f, 0.f};

  const int NT = K >> 6;
  const int ldsO = wave * 512;     // per-wave short offset within an 8KB unit

  // ---- prologue (issue order defines vmcnt math): a0a2(0), a1a3(0), b*(0), a0a2(1)
  GLOAD_LDS16(gA[0], &Abuf[0][0     + ldsO]);
  GLOAD_LDS16(gA[2], &Abuf[0][8192  + ldsO]);
  GLOAD_LDS16(gA[1], &Abuf[0][4096  + ldsO]);
  GLOAD_LDS16(gA[3], &Abuf[0][12288 + ldsO]);
#pragma unroll
  for (int r = 0; r < NREP; ++r) GLOAD_LDS16(gB[r], &Bbuf[0][r * 4096 + ldsO]);
  GLOAD_LDS16(gA[0] + 64, &Abuf[1][0    + ldsO]);
  GLOAD_LDS16(gA[2] + 64, &Abuf[1][8192 + ldsO]);

  for (int t = 0; t < NT; ++t) {
    const int cur = t & 1, nxt = cur ^ 1;
    int t1 = t + 1; if (t1 == NT) t1 = 0;
    int t2 = t + 2; if (t2 >= NT) t2 -= NT;
    const int ko1 = t1 << 6, ko2 = t2 << 6;
    const unsigned short* Al = Abuf[cur];
    const unsigned short* Bl = Bbuf[cur];
    bf16x8 af[4][2];
    bf16x8 bfr[NREP == 4 ? 4 : 2][2];

    // -------- phase 0: stage a1a3(t+1); tile-boundary counted wait; mh0 x n{0,1}
    GLOAD_LDS16(gA[1] + ko1, &Abuf[nxt][4096  + ldsO]);
    GLOAD_LDS16(gA[3] + ko1, &Abuf[nxt][12288 + ldsO]);
    asm volatile("s_waitcnt vmcnt(4)" ::: "memory");
    __builtin_amdgcn_s_barrier();
    __builtin_amdgcn_sched_barrier(0);
#pragma unroll
    for (int kk = 0; kk < 2; ++kk) {
#pragma unroll
      for (int n = 0; n < 2; ++n)
        bfr[n][kk] = *(const bf16x8*)((const char*)Bl +
                       swz((wn * (NREP * 16) + n * 16 + lr) * 128 + kk * 64 + khb));
#pragma unroll
      for (int m = 0; m < 4; ++m)
        af[m][kk] = *(const bf16x8*)((const char*)Al +
                       swz((wm * 128 + m * 16 + lr) * 128 + kk * 64 + khb));
    }
    __builtin_amdgcn_s_setprio(1);
#pragma unroll
    for (int kk = 0; kk < 2; ++kk)
#pragma unroll
      for (int m = 0; m < 4; ++m)
#pragma unroll
        for (int n = 0; n < 2; ++n)
          acc[m][n] = mfma16(af[m][kk], bfr[n][kk], acc[m][n]);
    __builtin_amdgcn_s_setprio(0);
    __builtin_amdgcn_sched_barrier(0);
    __builtin_amdgcn_s_barrier();

    if constexpr (NREP == 4) {
      // -------- phase 1: stage b0b1(t+1); mh0 x n{2,3}
      GLOAD_LDS16(gB[0] + ko1, &Bbuf[nxt][0    + ldsO]);
      GLOAD_LDS16(gB[1] + ko1, &Bbuf[nxt][4096 + ldsO]);
#pragma unroll
      for (int kk = 0; kk < 2; ++kk)
#pragma unroll
        for (int n = 2; n < 4; ++n)
          bfr[n][kk] = *(const bf16x8*)((const char*)Bl +
                         swz((wn * 64 + n * 16 + lr) * 128 + kk * 64 + khb));
      __builtin_amdgcn_s_barrier();
      __builtin_amdgcn_sched_barrier(0);
      __builtin_amdgcn_s_setprio(1);
#pragma unroll
      for (int kk = 0; kk < 2; ++kk)
#pragma unroll
        for (int m = 0; m < 4; ++m)
#pragma unroll
          for (int n = 2; n < 4; ++n)
            acc[m][n] = mfma16(af[m][kk], bfr[n][kk], acc[m][n]);
      __builtin_amdgcn_s_setprio(0);
      __builtin_amdgcn_sched_barrier(0);
      __builtin_amdgcn_s_barrier();

      // -------- phase 2: stage b2b3(t+1); mh1 x n{0,1}
      GLOAD_LDS16(gB[2] + ko1, &Bbuf[nxt][8192  + ldsO]);
      GLOAD_LDS16(gB[3] + ko1, &Bbuf[nxt][12288 + ldsO]);
#pragma unroll
      for (int kk = 0; kk < 2; ++kk)
#pragma unroll
        for (int m = 0; m < 4; ++m)
          af[m][kk] = *(const bf16x8*)((const char*)Al +
                        swz((wm * 128 + 64 + m * 16 + lr) * 128 + kk * 64 + khb));
      __builtin_amdgcn_s_barrier();
      __builtin_amdgcn_sched_barrier(0);
      __builtin_amdgcn_s_setprio(1);
#pragma unroll
      for (int kk = 0; kk < 2; ++kk)
#pragma unroll
        for (int m = 0; m < 4; ++m)
#pragma unroll
          for (int n = 0; n < 2; ++n)
            acc[4 + m][n] = mfma16(af[m][kk], bfr[n][kk], acc[4 + m][n]);
      __builtin_amdgcn_s_setprio(0);
      __builtin_amdgcn_sched_barrier(0);
      __builtin_amdgcn_s_barrier();

      // -------- phase 3: stage a0a2(t+2) into cur (free since phase 0/1); mh1 x n{2,3}
      GLOAD_LDS16(gA[0] + ko2, &Abuf[cur][0    + ldsO]);
      GLOAD_LDS16(gA[2] + ko2, &Abuf[cur][8192 + ldsO]);
      __builtin_amdgcn_s_barrier();
      __builtin_amdgcn_sched_barrier(0);
      __builtin_amdgcn_s_setprio(1);
#pragma unroll
      for (int kk = 0; kk < 2; ++kk)
#pragma unroll
        for (int m = 0; m < 4; ++m)
#pragma unroll
          for (int n = 2; n < 4; ++n)
            acc[4 + m][n] = mfma16(af[m][kk], bfr[n][kk], acc[4 + m][n]);
      __builtin_amdgcn_s_setprio(0);
      __builtin_amdgcn_sched_barrier(0);
      __builtin_amdgcn_s_barrier();
    } else {
      // -------- phase 1 (NREP=2): stage b0b1(t+1) + a0a2(t+2); mh1 x n{0,1}
      GLOAD_LDS16(gB[0] + ko1, &Bbuf[nxt][0    + ldsO]);
      GLOAD_LDS16(gB[1] + ko1, &Bbuf[nxt][4096 + ldsO]);
      GLOAD_LDS16(gA[0] + ko2, &Abuf[cur][0    + ldsO]);
      GLOAD_LDS16(gA[2] + ko2, &Abuf[cur][8192 + ldsO]);
#pragma unroll
      for (int kk = 0; kk < 2; ++kk)
#pragma unroll
        for (int m = 0; m < 4; ++m)
          af[m][kk] = *(const bf16x8*)((const char*)Al +
                        swz((wm * 128 + 64 + m * 16 + lr) * 128 + kk * 64 + khb));
      __builtin_amdgcn_s_barrier();
      __builtin_amdgcn_sched_barrier(0);
      __builtin_amdgcn_s_setprio(1);
#pragma unroll
      for (int kk = 0; kk < 2; ++kk)
#pragma unroll
        for (int m = 0; m < 4; ++m)
#pragma unroll
          for (int n = 0; n < 2; ++n)
            acc[4 + m][n] = mfma16(af[m][kk], bfr[n][kk], acc[4 + m][n]);
      __builtin_amdgcn_s_setprio(0);
      __builtin_amdgcn_sched_barrier(0);
      __builtin_amdgcn_s_barrier();
    }
  }
  asm volatile("s_waitcnt vmcnt(0)" ::: "memory");   // drain wrapped stages

  const int rb = (lane >> 4) * 4;
  if constexpr (EPI == 5) {
    const int jt = blockIdx.y;
#pragma unroll
    for (int m = 0; m < 8; ++m) {
      float ps[4] = {0.f, 0.f, 0.f, 0.f};
#pragma unroll
      for (int n = 0; n < NREP; ++n) {
#pragma unroll
        for (int r = 0; r < 4; ++r) {
          long gr = row0 + wm * 128 + m * 16 + rb + r;
          long gc = col0 + wn * NREP * 16 + n * 16 + lr;
          float e = exp2f(acc[m][n][r] * scale);   // scale includes log2e
          ((unsigned short*)Dp)[(long)z * Dz + gr * ldd + gc] = f2bf(e);
          ps[r] += e;
        }
      }
#pragma unroll
      for (int r = 0; r < 4; ++r) {
        ps[r] += __shfl_xor(ps[r], 1);
        ps[r] += __shfl_xor(ps[r], 2);
        ps[r] += __shfl_xor(ps[r], 4);
        ps[r] += __shfl_xor(ps[r], 8);
      }
      if (lr == 0) {
#pragma unroll
        for (int r = 0; r < 4; ++r) {
          long gr = row0 + wm * 128 + m * 16 + rb + r;
          rs[((long)z * 1024 + gr) * 16 + jt * 4 + wn] = ps[r];
        }
      }
    }
    return;
  }

#pragma unroll
  for (int m = 0; m < 8; ++m) {
#pragma unroll
    for (int n = 0; n < NREP; ++n) {
#pragma unroll
      for (int r = 0; r < 4; ++r) {
        long gr = row0 + wm * 128 + m * 16 + rb + r;
        long gc = col0 + wn * NREP * 16 + n * 16 + lr;
        float v = acc[m][n][r];
        if constexpr (EPI == 0) {
          v += bias[gc];
          ((unsigned short*)Dp)[(long)z * Dz + gr * ldd + gc] = f2bf(v);
        } else if constexpr (EPI == 1) {
          v += bias[gr];
          ((unsigned short*)Dp)[(long)z * Dz + gr * ldd + gc] = f2bf(v);
        } else if constexpr (EPI == 6) {
          v *= dinv_s[(int)(wm * 128 + m * 16 + rb + r)];
          ((unsigned short*)Dp)[(long)z * Dz + gr * ldd + gc] = f2bf(v);
        } else {
          long o = (long)z * (512L * 1024L) + gr * 1024L + gc;
          ((float*)Dp)[o] = v + bias[gr] + residual[o];
        }
      }
    }
  }
}

extern "C" void kernel_launch(void* const* d_in, const int* in_sizes, int n_in,
                              void* d_out, int out_size, void* d_ws, size_t ws_size,
                              hipStream_t stream) {
  const float* x     = (const float*)d_in[0];
  const float* gamma = (const float*)d_in[1];
  const float* beta  = (const float*)d_in[2];
  const float* wq    = (const float*)d_in[3];
  const float* bq    = (const float*)d_in[4];
  const float* wk    = (const float*)d_in[5];
  const float* bk    = (const float*)d_in[6];
  const float* wv    = (const float*)d_in[7];
  const float* bv    = (const float*)d_in[8];
  const float* wo    = (const float*)d_in[9];
  const float* bo    = (const float*)d_in[10];
  float* out = (float*)d_out;

  char* ws = (char*)d_ws;
  unsigned short* ht   = (unsigned short*)(ws + 0);           // [16384,512] bf16
  unsigned short* qkt  = (unsigned short*)(ws + 16777216);    // [16384,1024] bf16 (q | k)
  unsigned short* vv   = (unsigned short*)(ws + 50331648);    // [512,16384] bf16
  unsigned short* ot   = (unsigned short*)(ws + 67108864);    // [16,1024,512] bf16
  unsigned short* S    = (unsigned short*)(ws + 83886080);    // [16,1024,1024] bf16 (P unnorm)
  unsigned short* wqkb = (unsigned short*)(ws + 117440512);   // [1024,512] bf16
  unsigned short* wvb  = (unsigned short*)(ws + 119537664);   // [512,512] bf16
  unsigned short* wob  = (unsigned short*)(ws + 120061952);   // [512,512] bf16
  float* bqk           = (float*)(ws + 120586240);            // [1024] f32
  float* stats         = (float*)(ws + 120590336);            // [512,2] f32
  float* rs            = (float*)(ws + 120594432);            // [16,1024,16] f32 partial rowsums

  gn_statsW<<<512, 256, 0, stream>>>(x, stats, wq, wk, wv, wo, bq, bk,
                                     wqkb, wvb, wob, bqk);
  gn_apply<<<dim3(16, 8, 16), 256, 0, stream>>>(x, stats, gamma, beta, ht);

  // G1: qkt[i, j] = sum_c ht[i,c] * wqk[j,c] + bqk[j]      (64x4 = 256 blocks)
  gemm256<4, 0><<<dim3(64, 4, 1), 512, 0, stream>>>(ht, 512, 0, wqkb, 512, 0,
                                                    qkt, 1024, 0, bqk, 0.f, 512, nullptr, nullptr);
  // G2: vv[c, t] = sum_k wv[c,k] * ht[t,k] + bv[c]         (2x128 = 256 blocks)
  gemm256<2, 1><<<dim3(2, 128, 1), 512, 0, stream>>>(wvb, 512, 0, ht, 512, 0,
                                                     vv, 16384, 0, bv, 0.f, 512, nullptr, nullptr);
  // G3: S[b,i,j] = exp2(scale' * sum_c q[i,c]*k[j,c]), partial rowsums -> rs  (4x4x16)
  gemm256<4, 5><<<dim3(4, 4, 16), 512, 0, stream>>>(qkt, 1024, 1048576L, qkt + 512, 1024, 1048576L,
                                                    S, 1024, 1048576L, nullptr,
                                                    0.06375871416f, 512, nullptr, rs);
  // G4: ot[b, i, c] = (sum_j P[b,i,j] * vv[c, b*N+j]) / rowsum   (4x4x16)
  gemm256<2, 6><<<dim3(4, 4, 16), 512, 0, stream>>>(S, 1024, 1048576L,
                                                    vv, 16384, 1024,
                                                    ot, 512, 524288L, nullptr, 0.f, 1024, nullptr, rs);
  // G5: out[b,o,n] = x + bo[o] + sum_c wo[o,c] * ot[b,n,c]       (2x8x16)
  gemm256<2, 4><<<dim3(2, 8, 16), 512, 0, stream>>>(wob, 512, 0, ot, 512, 524288L,
                                                    out, 0, 0, bo, 0.f, 512, x, nullptr);
}

// Round 8
// 155.269 us; speedup vs baseline: 1.0773x; 1.0773x over previous
//
#include <hip/hip_runtime.h>

typedef __attribute__((ext_vector_type(4))) float f32x4;
typedef __attribute__((ext_vector_type(8))) __bf16 bf16x8;
typedef __attribute__((ext_vector_type(4))) unsigned short us4;
typedef __attribute__((ext_vector_type(8))) unsigned short us8;

#define B_  16
#define C_  512
#define N_  1024
#define G_  32
#define GS  16

__device__ inline unsigned short f2bf(float f) {
  unsigned u = __builtin_bit_cast(unsigned, f);
  u += 0x7fffu + ((u >> 16) & 1u);
  return (unsigned short)(u >> 16);
}

#define GLOAD_LDS16(gp, lp) __builtin_amdgcn_global_load_lds( \
    (const __attribute__((address_space(1))) unsigned int*)(gp), \
    (__attribute__((address_space(3))) unsigned int*)(lp), 16, 0, 0)

// ---------------- GroupNorm ----------------
__global__ __launch_bounds__(256) void gn_stats(const float* __restrict__ x,
                                                float* __restrict__ stats) {
  int bg = blockIdx.x;                       // b*32+g
  const float* xp = x + (long)bg * (GS * N_);
  int tid = threadIdx.x;
  float s = 0.f, ss = 0.f;
  for (int i = tid * 4; i < GS * N_; i += 1024) {
    f32x4 v = *(const f32x4*)&xp[i];
    s += v.x + v.y + v.z + v.w;
    ss += v.x * v.x + v.y * v.y + v.z * v.z + v.w * v.w;
  }
  __shared__ float r1[256], r2[256];
  r1[tid] = s; r2[tid] = ss; __syncthreads();
  for (int off = 128; off > 0; off >>= 1) {
    if (tid < off) { r1[tid] += r1[tid + off]; r2[tid] += r2[tid + off]; }
    __syncthreads();
  }
  if (tid == 0) {
    float mean = r1[0] * (1.f / (GS * N_));
    float var  = r2[0] * (1.f / (GS * N_)) - mean * mean;
    stats[bg * 2]     = mean;
    stats[bg * 2 + 1] = rsqrtf(var + 1e-6f);
  }
}

// normalize + transpose: x[b,c,n] -> ht[(b*N+n)*C + c]  (bf16)
__global__ __launch_bounds__(256) void gn_apply(const float* __restrict__ x,
                                                const float* __restrict__ stats,
                                                const float* __restrict__ gamma,
                                                const float* __restrict__ beta,
                                                unsigned short* __restrict__ ht) {
  int b = blockIdx.z, ct = blockIdx.y, nt = blockIdx.x;
  int c0 = ct * 64, n0 = nt * 64;
  int tid = threadIdx.x;
  __shared__ unsigned short L[64 * 68];
  const float* xp = x + ((long)b * C_ + c0) * N_ + n0;
#pragma unroll
  for (int i = 0; i < 4; ++i) {
    int li = tid + i * 256;        // 0..1023
    int row = li >> 4;             // c offset 0..63
    int col4 = (li & 15) * 4;      // n offset
    f32x4 v = *(const f32x4*)&xp[(long)row * N_ + col4];
    int c = c0 + row;
    float mean = stats[(b * G_ + (c >> 4)) * 2];
    float rstd = stats[(b * G_ + (c >> 4)) * 2 + 1];
    float gm = gamma[c] * rstd;
    float bt = beta[c] - mean * gm;
    us4 o;
    o.x = f2bf(v.x * gm + bt); o.y = f2bf(v.y * gm + bt);
    o.z = f2bf(v.z * gm + bt); o.w = f2bf(v.w * gm + bt);
    *(us4*)&L[row * 68 + col4] = o;
  }
  __syncthreads();
#pragma unroll
  for (int i = 0; i < 2; ++i) {
    int s = tid + i * 256;         // 0..511
    int n = s >> 3;
    int cs = (s & 7) * 8;
    us8 o;
#pragma unroll
    for (int j = 0; j < 8; ++j) o[j] = L[(cs + j) * 68 + n];
    *(us8*)&ht[((long)b * N_ + n0 + n) * C_ + c0 + cs] = o;
  }
}

// ---------------- weight conversion + bvo = wo . bv ----------------
__global__ __launch_bounds__(256) void convert_w(const float* __restrict__ wq, const float* __restrict__ wk,
                                                 const float* __restrict__ wo,
                                                 const float* __restrict__ bq, const float* __restrict__ bk,
                                                 const float* __restrict__ bv,
                                                 unsigned short* __restrict__ wqk,
                                                 unsigned short* __restrict__ wob, float* __restrict__ bqk,
                                                 float* __restrict__ bvo) {
  long bid = blockIdx.x;
  int tid = threadIdx.x;
  long i = bid * 256 + tid;
  if (i < C_ * C_) {
    wqk[i]           = f2bf(wq[i]);
    wqk[C_ * C_ + i] = f2bf(wk[i]);
    wob[i]           = f2bf(wo[i]);
  }
  if (i < C_) { bqk[i] = bq[i]; bqk[C_ + i] = bk[i]; }
  if (bid >= 1024) {
    int o = (int)(bid - 1024) * 256 + tid;   // 0..511
    const float* wr = wo + (long)o * 512;
    float acc = 0.f;
    for (int c = 0; c < 512; c += 4) {
      f32x4 w4 = *(const f32x4*)&wr[c];
      f32x4 b4 = *(const f32x4*)&bv[c];
      acc += w4.x * b4.x + w4.y * b4.y + w4.z * b4.z + w4.w * b4.w;
    }
    bvo[o] = acc;
  }
}

// ---------------- wvT[k,c] = wv[c,k]  (64x64 f32 LDS tiles, bf16 out) ----------------
__global__ __launch_bounds__(256) void transpose_wv(const float* __restrict__ wv,
                                                    unsigned short* __restrict__ wvT) {
  int c0 = blockIdx.x * 64, k0 = blockIdx.y * 64;
  int tid = threadIdx.x;
  __shared__ float Lt[64][65];   // Lt[k_local][c_local]
#pragma unroll
  for (int i = 0; i < 4; ++i) {
    int lin = tid + i * 256;          // 0..1023
    int rr = lin >> 4;                // c offset 0..63
    int q4 = (lin & 15) * 4;          // k offset
    f32x4 v = *(const f32x4*)&wv[(long)(c0 + rr) * 512 + k0 + q4];
    Lt[q4 + 0][rr] = v.x; Lt[q4 + 1][rr] = v.y;
    Lt[q4 + 2][rr] = v.z; Lt[q4 + 3][rr] = v.w;
  }
  __syncthreads();
#pragma unroll
  for (int i = 0; i < 2; ++i) {
    int lin = tid + i * 256;          // 0..511
    int kk = lin >> 3;                // k offset 0..63
    int cc = (lin & 7) * 8;           // c offset
    us8 o;
#pragma unroll
    for (int j = 0; j < 8; ++j) o[j] = f2bf(Lt[kk][cc + j]);
    *(us8*)&wvT[(long)(k0 + kk) * 512 + c0 + cc] = o;
  }
}

// ---------------- WVO[o,k] = sum_c wob[o,c] * wvT[k,c]  (no LDS, L2-resident) ----------------
__device__ inline f32x4 mfma16(bf16x8 a, bf16x8 b, f32x4 c) {
  return __builtin_amdgcn_mfma_f32_16x16x32_bf16(a, b, c, 0, 0, 0);
}

__global__ __launch_bounds__(256) void wprod(const unsigned short* __restrict__ wob,
                                             const unsigned short* __restrict__ wvT,
                                             unsigned short* __restrict__ WVO) {
  int row0 = blockIdx.x * 64, col0 = blockIdx.y * 64;
  int tid = threadIdx.x, lane = tid & 63, w = tid >> 6;
  int lr = lane & 15, kh = (lane >> 4) * 8;
  f32x4 acc4[4];
#pragma unroll
  for (int n = 0; n < 4; ++n) acc4[n] = f32x4{0.f, 0.f, 0.f, 0.f};
  for (int k0 = 0; k0 < 512; k0 += 32) {
    bf16x8 af = *(const bf16x8*)&wob[(long)(row0 + w * 16 + lr) * 512 + k0 + kh];
#pragma unroll
    for (int n = 0; n < 4; ++n) {
      bf16x8 bf8 = *(const bf16x8*)&wvT[(long)(col0 + n * 16 + lr) * 512 + k0 + kh];
      acc4[n] = mfma16(af, bf8, acc4[n]);
    }
  }
  int rb = (lane >> 4) * 4;
#pragma unroll
  for (int n = 0; n < 4; ++n)
#pragma unroll
    for (int r = 0; r < 4; ++r)
      WVO[(long)(row0 + w * 16 + rb + r) * 512 + col0 + n * 16 + lr] = f2bf(acc4[n][r]);
}

// ---------------- 256x(256|128) 8-wave MFMA GEMM, 2-phase counted-vmcnt (R4 core) ----------------
__device__ inline int swz(int b) { return b ^ (((b >> 9) & 1) << 5); }

// EPI: 0 = +bias[col], bf16 store      1 = +bias[row], bf16 store
//      5 = exp2(v*scale) bf16 store + per-row partial sums -> rs
//      7 = v*dinv(row) + bias[col] + residual, f32x4 transposed store out[z, col, row]
// XSWZ: bijective XCD remap for exact 4x4x16 = 256-block grids
template<int NREP, int EPI, int XSWZ>
__global__ __launch_bounds__(512, 2) void gemm256(
    const unsigned short* __restrict__ A, long lda, long Az,
    const unsigned short* __restrict__ Bm, long ldb, long Bz,
    void* __restrict__ Dp, long ldd, long Dz,
    const float* __restrict__ bias, float scale, int K,
    const float* __restrict__ residual, float* __restrict__ rs) {
  constexpr int BN = NREP * 64;
  int bx = blockIdx.x, by = blockIdx.y, bz = blockIdx.z;
  if constexpr (XSWZ) {
    int lin = bx + 4 * (by + 4 * bz);        // hw linear, x-fastest (grid 4x4x16)
    int l2  = (lin & 7) * 32 + (lin >> 3);   // XCD k owns logical tiles k*32..k*32+31
    bx = l2 & 3; by = (l2 >> 2) & 3; bz = l2 >> 4;
  }
  const int z = bz;
  const long row0 = (long)bx * 256;
  const long col0 = (long)by * BN;
  const int tid  = threadIdx.x;
  const int lane = tid & 63;
  const int wave = tid >> 6;
  const int wm = wave >> 2;
  const int wn = wave & 3;
  const int lr = lane & 15;
  const int khb = (lane >> 4) * 16;

  __shared__ unsigned short Abuf[2][16384];
  __shared__ unsigned short Bbuf[2][NREP * 4096];
  __shared__ float sred[256];

  const unsigned short* Ab = A  + (long)z * Az;
  const unsigned short* Bb = Bm + (long)z * Bz;

  if constexpr (EPI == 7) {
    if (tid < 256) {
      const float* rp = rs + ((long)z * 1024 + row0 + tid) * 16;
      float s = 0.f;
#pragma unroll
      for (int i = 0; i < 16; ++i) s += rp[i];
      sred[tid] = 1.f / s;
    }
    asm volatile("s_waitcnt lgkmcnt(0)" ::: "memory");
  }

  const unsigned short* gA[4];
#pragma unroll
  for (int r = 0; r < 4; ++r) {
    int L = swz(r * 8192 + tid * 16);
    gA[r] = Ab + (row0 + (L >> 7)) * lda + ((L & 127) >> 1);
  }
  const unsigned short* gB[NREP];
#pragma unroll
  for (int r = 0; r < NREP; ++r) {
    int L = swz(r * 8192 + tid * 16);
    gB[r] = Bb + (col0 + (L >> 7)) * ldb + ((L & 127) >> 1);
  }

  f32x4 acc[8][NREP];
#pragma unroll
  for (int m = 0; m < 8; ++m)
#pragma unroll
    for (int n = 0; n < NREP; ++n) acc[m][n] = f32x4{0.f, 0.f, 0.f, 0.f};

  const int NT = K >> 6;
  // prologue: stage tile 0 into buf 0
#pragma unroll
  for (int r = 0; r < 4; ++r)    GLOAD_LDS16(gA[r], &Abuf[0][r * 4096 + wave * 512]);
#pragma unroll
  for (int r = 0; r < NREP; ++r) GLOAD_LDS16(gB[r], &Bbuf[0][r * 4096 + wave * 512]);

  for (int t = 0; t < NT; ++t) {
    int tn = t + 1; if (tn == NT) tn = 0;          // wrap keeps vmcnt math uniform
    const long ko = (long)tn << 6;
    const int nb = (t + 1) & 1;
#pragma unroll
    for (int r = 0; r < 4; ++r)    GLOAD_LDS16(gA[r] + ko, &Abuf[nb][r * 4096 + wave * 512]);
#pragma unroll
    for (int r = 0; r < NREP; ++r) GLOAD_LDS16(gB[r] + ko, &Bbuf[nb][r * 4096 + wave * 512]);
    // counted wait: current tile's (oldest) loads landed; next tile's stay in flight
    if constexpr (NREP == 4) asm volatile("s_waitcnt vmcnt(8)" ::: "memory");
    else                     asm volatile("s_waitcnt vmcnt(6)" ::: "memory");
    __builtin_amdgcn_s_barrier();
    __builtin_amdgcn_sched_barrier(0);
    const unsigned short* Al = Abuf[t & 1];
    const unsigned short* Bl = Bbuf[t & 1];
#pragma unroll
    for (int kk = 0; kk < 2; ++kk) {
      bf16x8 af[8], bfr[NREP];
#pragma unroll
      for (int m = 0; m < 8; ++m) {
        int Pb = swz((wm * 128 + m * 16 + lr) * 128 + kk * 64 + khb);
        af[m] = *(const bf16x8*)((const char*)Al + Pb);
      }
#pragma unroll
      for (int n = 0; n < NREP; ++n) {
        int Pb = swz((wn * (NREP * 16) + n * 16 + lr) * 128 + kk * 64 + khb);
        bfr[n] = *(const bf16x8*)((const char*)Bl + Pb);
      }
      __builtin_amdgcn_s_setprio(1);
#pragma unroll
      for (int m = 0; m < 8; ++m)
#pragma unroll
        for (int n = 0; n < NREP; ++n)
          acc[m][n] = mfma16(af[m], bfr[n], acc[m][n]);
      __builtin_amdgcn_s_setprio(0);
    }
    __builtin_amdgcn_sched_barrier(0);
    __builtin_amdgcn_s_barrier();
    __builtin_amdgcn_sched_barrier(0);
  }
  asm volatile("s_waitcnt vmcnt(0)" ::: "memory");   // drain wrapped stage

  const int rb = (lane >> 4) * 4;
  if constexpr (EPI == 5) {
    const int jt = by;
#pragma unroll
    for (int m = 0; m < 8; ++m) {
      float ps[4] = {0.f, 0.f, 0.f, 0.f};
#pragma unroll
      for (int n = 0; n < NREP; ++n) {
#pragma unroll
        for (int r = 0; r < 4; ++r) {
          long gr = row0 + wm * 128 + m * 16 + rb + r;
          long gc = col0 + wn * (NREP * 16) + n * 16 + lr;
          float e = exp2f(acc[m][n][r] * scale);   // scale includes log2e
          ((unsigned short*)Dp)[(long)z * Dz + gr * ldd + gc] = f2bf(e);
          ps[r] += e;
        }
      }
#pragma unroll
      for (int r = 0; r < 4; ++r) {
        ps[r] += __shfl_xor(ps[r], 1);
        ps[r] += __shfl_xor(ps[r], 2);
        ps[r] += __shfl_xor(ps[r], 4);
        ps[r] += __shfl_xor(ps[r], 8);
      }
      if (lr == 0) {
#pragma unroll
        for (int r = 0; r < 4; ++r) {
          long gr = row0 + wm * 128 + m * 16 + rb + r;
          rs[((long)z * 1024 + gr) * 16 + jt * 4 + wn] = ps[r];
        }
      }
    }
    return;
  }

  if constexpr (EPI == 7) {
#pragma unroll
    for (int m = 0; m < 8; ++m) {
      int lrow = wm * 128 + m * 16 + rb;
      long gr0 = row0 + lrow;
#pragma unroll
      for (int n = 0; n < NREP; ++n) {
        long gc = col0 + wn * (NREP * 16) + n * 16 + lr;
        long o = (long)z * (512L * 1024L) + gc * 1024L + gr0;
        f32x4 res = *(const f32x4*)&residual[o];
        float bb = bias[gc];
        f32x4 st;
#pragma unroll
        for (int r = 0; r < 4; ++r)
          st[r] = acc[m][n][r] * sred[lrow + r] + bb + res[r];
        *(f32x4*)&((float*)Dp)[o] = st;
      }
    }
    return;
  }

#pragma unroll
  for (int m = 0; m < 8; ++m) {
#pragma unroll
    for (int n = 0; n < NREP; ++n) {
#pragma unroll
      for (int r = 0; r < 4; ++r) {
        long gr = row0 + wm * 128 + m * 16 + rb + r;
        long gc = col0 + wn * (NREP * 16) + n * 16 + lr;
        float v = acc[m][n][r];
        if constexpr (EPI == 0) v += bias[gc];
        else                    v += bias[gr];
        ((unsigned short*)Dp)[(long)z * Dz + gr * ldd + gc] = f2bf(v);
      }
    }
  }
}

extern "C" void kernel_launch(void* const* d_in, const int* in_sizes, int n_in,
                              void* d_out, int out_size, void* d_ws, size_t ws_size,
                              hipStream_t stream) {
  const float* x     = (const float*)d_in[0];
  const float* gamma = (const float*)d_in[1];
  const float* beta  = (const float*)d_in[2];
  const float* wq    = (const float*)d_in[3];
  const float* bq    = (const float*)d_in[4];
  const float* wk    = (const float*)d_in[5];
  const float* bk    = (const float*)d_in[6];
  const float* wv    = (const float*)d_in[7];
  const float* bv    = (const float*)d_in[8];
  const float* wo    = (const float*)d_in[9];
  const float* bo    = (const float*)d_in[10];
  float* out = (float*)d_out;

  char* ws = (char*)d_ws;
  unsigned short* ht   = (unsigned short*)(ws + 0);           // [16384,512] bf16
  unsigned short* qkt  = (unsigned short*)(ws + 16777216);    // [16384,1024] bf16 (q | k)
  unsigned short* VWT  = (unsigned short*)(ws + 50331648);    // [512,16384] bf16 (wo.v)
  unsigned short* S    = (unsigned short*)(ws + 83886080);    // [16,1024,1024] bf16 (P unnorm)
  unsigned short* wqkb = (unsigned short*)(ws + 117440512);   // [1024,512] bf16
  unsigned short* wvT  = (unsigned short*)(ws + 119537664);   // [512,512] bf16 (k,c)
  unsigned short* wob  = (unsigned short*)(ws + 120061952);   // [512,512] bf16
  unsigned short* WVO  = (unsigned short*)(ws + 120586240);   // [512,512] bf16
  float* bqk           = (float*)(ws + 121110528);            // [1024] f32
  float* bvo           = (float*)(ws + 121114624);            // [512] f32
  float* stats         = (float*)(ws + 121116672);            // [512,2] f32
  float* rs            = (float*)(ws + 121122816);            // [16,1024,16] f32 partial rowsums

  convert_w<<<1026, 256, 0, stream>>>(wq, wk, wo, bq, bk, bv,
                                      wqkb, wob, bqk, bvo);
  transpose_wv<<<dim3(8, 8), 256, 0, stream>>>(wv, wvT);
  wprod<<<dim3(8, 8), 256, 0, stream>>>(wob, wvT, WVO);
  gn_stats<<<512, 256, 0, stream>>>(x, stats);
  gn_apply<<<dim3(16, 8, 16), 256, 0, stream>>>(x, stats, gamma, beta, ht);

  // G1: qkt[i, j] = sum_c ht[i,c] * wqk[j,c] + bqk[j]      (64x4 = 256 blocks)
  gemm256<4, 0, 0><<<dim3(64, 4, 1), 512, 0, stream>>>(ht, 512, 0, wqkb, 512, 0,
                                                       qkt, 1024, 0, bqk, 0.f, 512, nullptr, nullptr);
  // G2: VWT[o, t] = sum_k WVO[o,k] * ht[t,k] + bvo[o]      (2x128 = 256 blocks)
  gemm256<2, 1, 0><<<dim3(2, 128, 1), 512, 0, stream>>>(WVO, 512, 0, ht, 512, 0,
                                                        VWT, 16384, 0, bvo, 0.f, 512, nullptr, nullptr);
  // G3: P[b,i,j] = exp2(scale' * sum_c q[i,c]*k[j,c]), rowsum partials -> rs  (4x4x16, XCD-swz)
  gemm256<4, 5, 1><<<dim3(4, 4, 16), 512, 0, stream>>>(qkt, 1024, 1048576L, qkt + 512, 1024, 1048576L,
                                                       S, 1024, 1048576L, nullptr,
                                                       0.06375871416f, 512, nullptr, rs);
  // G4: out[b,o,n] = dinv_n * sum_j P[b,n,j] * VWT[o, b*N+j] + bo[o] + x[b,o,n]  (4x4x16, XCD-swz)
  gemm256<2, 7, 1><<<dim3(4, 4, 16), 512, 0, stream>>>(S, 1024, 1048576L,
                                                       VWT, 16384, 1024,
                                                       out, 0, 0, bo, 0.f, 1024, x, rs);
}

// Round 9
// 154.639 us; speedup vs baseline: 1.0817x; 1.0041x over previous
//
#include <hip/hip_runtime.h>

typedef __attribute__((ext_vector_type(4))) float f32x4;
typedef __attribute__((ext_vector_type(8))) __bf16 bf16x8;
typedef __attribute__((ext_vector_type(4))) unsigned short us4;
typedef __attribute__((ext_vector_type(8))) unsigned short us8;

#define B_  16
#define C_  512
#define N_  1024
#define G_  32
#define GS  16

__device__ inline unsigned short f2bf(float f) {
  unsigned u = __builtin_bit_cast(unsigned, f);
  u += 0x7fffu + ((u >> 16) & 1u);
  return (unsigned short)(u >> 16);
}

#define GLOAD_LDS16(gp, lp) __builtin_amdgcn_global_load_lds( \
    (const __attribute__((address_space(1))) unsigned int*)(gp), \
    (__attribute__((address_space(3))) unsigned int*)(lp), 16, 0, 0)

// ---------------- GroupNorm ----------------
__global__ __launch_bounds__(256) void gn_stats(const float* __restrict__ x,
                                                float* __restrict__ stats) {
  int bg = blockIdx.x;                       // b*32+g
  const float* xp = x + (long)bg * (GS * N_);
  int tid = threadIdx.x;
  float s = 0.f, ss = 0.f;
  for (int i = tid * 4; i < GS * N_; i += 1024) {
    f32x4 v = *(const f32x4*)&xp[i];
    s += v.x + v.y + v.z + v.w;
    ss += v.x * v.x + v.y * v.y + v.z * v.z + v.w * v.w;
  }
  __shared__ float r1[256], r2[256];
  r1[tid] = s; r2[tid] = ss; __syncthreads();
  for (int off = 128; off > 0; off >>= 1) {
    if (tid < off) { r1[tid] += r1[tid + off]; r2[tid] += r2[tid + off]; }
    __syncthreads();
  }
  if (tid == 0) {
    float mean = r1[0] * (1.f / (GS * N_));
    float var  = r2[0] * (1.f / (GS * N_)) - mean * mean;
    stats[bg * 2]     = mean;
    stats[bg * 2 + 1] = rsqrtf(var + 1e-6f);
  }
}

// normalize + transpose: x[b,c,n] -> ht[(b*N+n)*C + c]  (bf16)
__global__ __launch_bounds__(256) void gn_apply(const float* __restrict__ x,
                                                const float* __restrict__ stats,
                                                const float* __restrict__ gamma,
                                                const float* __restrict__ beta,
                                                unsigned short* __restrict__ ht) {
  int b = blockIdx.z, ct = blockIdx.y, nt = blockIdx.x;
  int c0 = ct * 64, n0 = nt * 64;
  int tid = threadIdx.x;
  __shared__ unsigned short L[64 * 68];
  const float* xp = x + ((long)b * C_ + c0) * N_ + n0;
#pragma unroll
  for (int i = 0; i < 4; ++i) {
    int li = tid + i * 256;        // 0..1023
    int row = li >> 4;             // c offset 0..63
    int col4 = (li & 15) * 4;      // n offset
    f32x4 v = *(const f32x4*)&xp[(long)row * N_ + col4];
    int c = c0 + row;
    float mean = stats[(b * G_ + (c >> 4)) * 2];
    float rstd = stats[(b * G_ + (c >> 4)) * 2 + 1];
    float gm = gamma[c] * rstd;
    float bt = beta[c] - mean * gm;
    us4 o;
    o.x = f2bf(v.x * gm + bt); o.y = f2bf(v.y * gm + bt);
    o.z = f2bf(v.z * gm + bt); o.w = f2bf(v.w * gm + bt);
    *(us4*)&L[row * 68 + col4] = o;
  }
  __syncthreads();
#pragma unroll
  for (int i = 0; i < 2; ++i) {
    int s = tid + i * 256;         // 0..511
    int n = s >> 3;
    int cs = (s & 7) * 8;
    us8 o;
#pragma unroll
    for (int j = 0; j < 8; ++j) o[j] = L[(cs + j) * 68 + n];
    *(us8*)&ht[((long)b * N_ + n0 + n) * C_ + c0 + cs] = o;
  }
}

// ---------------- weight conversion + bvo = wo . bv ----------------
__global__ __launch_bounds__(256) void convert_w(const float* __restrict__ wq, const float* __restrict__ wk,
                                                 const float* __restrict__ wo,
                                                 const float* __restrict__ bq, const float* __restrict__ bk,
                                                 const float* __restrict__ bv,
                                                 unsigned short* __restrict__ wqk,
                                                 unsigned short* __restrict__ wob, float* __restrict__ bqk,
                                                 float* __restrict__ bvo) {
  long bid = blockIdx.x;
  int tid = threadIdx.x;
  long i = bid * 256 + tid;
  if (i < C_ * C_) {
    wqk[i]           = f2bf(wq[i]);
    wqk[C_ * C_ + i] = f2bf(wk[i]);
    wob[i]           = f2bf(wo[i]);
  }
  if (i < C_) { bqk[i] = bq[i]; bqk[C_ + i] = bk[i]; }
  if (bid >= 1024) {
    int o = (int)(bid - 1024) * 256 + tid;   // 0..511
    const float* wr = wo + (long)o * 512;
    float acc = 0.f;
    for (int c = 0; c < 512; c += 4) {
      f32x4 w4 = *(const f32x4*)&wr[c];
      f32x4 b4 = *(const f32x4*)&bv[c];
      acc += w4.x * b4.x + w4.y * b4.y + w4.z * b4.z + w4.w * b4.w;
    }
    bvo[o] = acc;
  }
}

// ---------------- wvT[k,c] = wv[c,k]  (64x64 f32 LDS tiles, bf16 out) ----------------
__global__ __launch_bounds__(256) void transpose_wv(const float* __restrict__ wv,
                                                    unsigned short* __restrict__ wvT) {
  int c0 = blockIdx.x * 64, k0 = blockIdx.y * 64;
  int tid = threadIdx.x;
  __shared__ float Lt[64][65];   // Lt[k_local][c_local]
#pragma unroll
  for (int i = 0; i < 4; ++i) {
    int lin = tid + i * 256;          // 0..1023
    int rr = lin >> 4;                // c offset 0..63
    int q4 = (lin & 15) * 4;          // k offset
    f32x4 v = *(const f32x4*)&wv[(long)(c0 + rr) * 512 + k0 + q4];
    Lt[q4 + 0][rr] = v.x; Lt[q4 + 1][rr] = v.y;
    Lt[q4 + 2][rr] = v.z; Lt[q4 + 3][rr] = v.w;
  }
  __syncthreads();
#pragma unroll
  for (int i = 0; i < 2; ++i) {
    int lin = tid + i * 256;          // 0..511
    int kk = lin >> 3;                // k offset 0..63
    int cc = (lin & 7) * 8;           // c offset
    us8 o;
#pragma unroll
    for (int j = 0; j < 8; ++j) o[j] = f2bf(Lt[kk][cc + j]);
    *(us8*)&wvT[(long)(k0 + kk) * 512 + c0 + cc] = o;
  }
}

// ---------------- WVO[o,k] = sum_c wob[o,c] * wvT[k,c]  (no LDS, L2-resident) ----------------
__device__ inline f32x4 mfma16(bf16x8 a, bf16x8 b, f32x4 c) {
  return __builtin_amdgcn_mfma_f32_16x16x32_bf16(a, b, c, 0, 0, 0);
}

__global__ __launch_bounds__(256) void wprod(const unsigned short* __restrict__ wob,
                                             const unsigned short* __restrict__ wvT,
                                             unsigned short* __restrict__ WVO) {
  int row0 = blockIdx.x * 64, col0 = blockIdx.y * 64;
  int tid = threadIdx.x, lane = tid & 63, w = tid >> 6;
  int lr = lane & 15, kh = (lane >> 4) * 8;
  f32x4 acc4[4];
#pragma unroll
  for (int n = 0; n < 4; ++n) acc4[n] = f32x4{0.f, 0.f, 0.f, 0.f};
  for (int k0 = 0; k0 < 512; k0 += 32) {
    bf16x8 af = *(const bf16x8*)&wob[(long)(row0 + w * 16 + lr) * 512 + k0 + kh];
#pragma unroll
    for (int n = 0; n < 4; ++n) {
      bf16x8 bf8 = *(const bf16x8*)&wvT[(long)(col0 + n * 16 + lr) * 512 + k0 + kh];
      acc4[n] = mfma16(af, bf8, acc4[n]);
    }
  }
  int rb = (lane >> 4) * 4;
#pragma unroll
  for (int n = 0; n < 4; ++n)
#pragma unroll
    for (int r = 0; r < 4; ++r)
      WVO[(long)(row0 + w * 16 + rb + r) * 512 + col0 + n * 16 + lr] = f2bf(acc4[n][r]);
}

// ---------------- 256x(256|128) 8-wave MFMA GEMM, 2-phase counted-vmcnt (R4 core) ----------------
__device__ inline int swz(int b) { return b ^ (((b >> 9) & 1) << 5); }

// EPI: 0 = +bias[col], bf16 store      1 = +bias[row], bf16 store
//      5 = exp2(v*scale) bf16 store + per-row partial sums -> rs
//      7 = v*dinv(row) + bias[col] + residual, f32x4 transposed store out[z, col, row]
// bf16 epilogues use LDS repack -> coalesced us8 stores
// XSWZ: bijective XCD remap for exact 4x4x16 = 256-block grids
template<int NREP, int EPI, int XSWZ>
__global__ __launch_bounds__(512, 2) void gemm256(
    const unsigned short* __restrict__ A, long lda, long Az,
    const unsigned short* __restrict__ Bm, long ldb, long Bz,
    void* __restrict__ Dp, long ldd, long Dz,
    const float* __restrict__ bias, float scale, int K,
    const float* __restrict__ residual, float* __restrict__ rs) {
  constexpr int BN = NREP * 64;
  int bx = blockIdx.x, by = blockIdx.y, bz = blockIdx.z;
  if constexpr (XSWZ) {
    int lin = bx + 4 * (by + 4 * bz);        // hw linear, x-fastest (grid 4x4x16)
    int l2  = (lin & 7) * 32 + (lin >> 3);   // XCD k owns logical tiles k*32..k*32+31
    bx = l2 & 3; by = (l2 >> 2) & 3; bz = l2 >> 4;
  }
  const int z = bz;
  const long row0 = (long)bx * 256;
  const long col0 = (long)by * BN;
  const int tid  = threadIdx.x;
  const int lane = tid & 63;
  const int wave = tid >> 6;
  const int wm = wave >> 2;
  const int wn = wave & 3;
  const int lr = lane & 15;
  const int khb = (lane >> 4) * 16;

  __shared__ unsigned short Abuf[2][16384];
  __shared__ unsigned short Bbuf[2][NREP * 4096];
  __shared__ float sred[256];

  const unsigned short* Ab = A  + (long)z * Az;
  const unsigned short* Bb = Bm + (long)z * Bz;

  if constexpr (EPI == 7) {
    if (tid < 256) {
      const float* rp = rs + ((long)z * 1024 + row0 + tid) * 16;
      float s = 0.f;
#pragma unroll
      for (int i = 0; i < 16; ++i) s += rp[i];
      sred[tid] = 1.f / s;
    }
    asm volatile("s_waitcnt lgkmcnt(0)" ::: "memory");
  }

  const unsigned short* gA[4];
#pragma unroll
  for (int r = 0; r < 4; ++r) {
    int L = swz(r * 8192 + tid * 16);
    gA[r] = Ab + (row0 + (L >> 7)) * lda + ((L & 127) >> 1);
  }
  const unsigned short* gB[NREP];
#pragma unroll
  for (int r = 0; r < NREP; ++r) {
    int L = swz(r * 8192 + tid * 16);
    gB[r] = Bb + (col0 + (L >> 7)) * ldb + ((L & 127) >> 1);
  }

  f32x4 acc[8][NREP];
#pragma unroll
  for (int m = 0; m < 8; ++m)
#pragma unroll
    for (int n = 0; n < NREP; ++n) acc[m][n] = f32x4{0.f, 0.f, 0.f, 0.f};

  const int NT = K >> 6;
  // prologue: stage tile 0 into buf 0
#pragma unroll
  for (int r = 0; r < 4; ++r)    GLOAD_LDS16(gA[r], &Abuf[0][r * 4096 + wave * 512]);
#pragma unroll
  for (int r = 0; r < NREP; ++r) GLOAD_LDS16(gB[r], &Bbuf[0][r * 4096 + wave * 512]);

  for (int t = 0; t < NT; ++t) {
    int tn = t + 1; if (tn == NT) tn = 0;          // wrap keeps vmcnt math uniform
    const long ko = (long)tn << 6;
    const int nb = (t + 1) & 1;
#pragma unroll
    for (int r = 0; r < 4; ++r)    GLOAD_LDS16(gA[r] + ko, &Abuf[nb][r * 4096 + wave * 512]);
#pragma unroll
    for (int r = 0; r < NREP; ++r) GLOAD_LDS16(gB[r] + ko, &Bbuf[nb][r * 4096 + wave * 512]);
    // counted wait: current tile's (oldest) loads landed; next tile's stay in flight
    if constexpr (NREP == 4) asm volatile("s_waitcnt vmcnt(8)" ::: "memory");
    else                     asm volatile("s_waitcnt vmcnt(6)" ::: "memory");
    __builtin_amdgcn_s_barrier();
    __builtin_amdgcn_sched_barrier(0);
    const unsigned short* Al = Abuf[t & 1];
    const unsigned short* Bl = Bbuf[t & 1];
#pragma unroll
    for (int kk = 0; kk < 2; ++kk) {
      bf16x8 af[8], bfr[NREP];
#pragma unroll
      for (int m = 0; m < 8; ++m) {
        int Pb = swz((wm * 128 + m * 16 + lr) * 128 + kk * 64 + khb);
        af[m] = *(const bf16x8*)((const char*)Al + Pb);
      }
#pragma unroll
      for (int n = 0; n < NREP; ++n) {
        int Pb = swz((wn * (NREP * 16) + n * 16 + lr) * 128 + kk * 64 + khb);
        bfr[n] = *(const bf16x8*)((const char*)Bl + Pb);
      }
      __builtin_amdgcn_s_setprio(1);
#pragma unroll
      for (int m = 0; m < 8; ++m)
#pragma unroll
        for (int n = 0; n < NREP; ++n)
          acc[m][n] = mfma16(af[m], bfr[n], acc[m][n]);
      __builtin_amdgcn_s_setprio(0);
    }
    __builtin_amdgcn_sched_barrier(0);
    __builtin_amdgcn_s_barrier();
    __builtin_amdgcn_sched_barrier(0);
  }
  asm volatile("s_waitcnt vmcnt(0)" ::: "memory");   // drain wrapped stage
  __builtin_amdgcn_s_barrier();                      // all DMA landed before Abuf reuse

  const int rb = (lane >> 4) * 4;

  if constexpr (EPI == 7) {
#pragma unroll
    for (int m = 0; m < 8; ++m) {
      int lrow = wm * 128 + m * 16 + rb;
      long gr0 = row0 + lrow;
#pragma unroll
      for (int n = 0; n < NREP; ++n) {
        long gc = col0 + wn * (NREP * 16) + n * 16 + lr;
        long o = (long)z * (512L * 1024L) + gc * 1024L + gr0;
        f32x4 res = *(const f32x4*)&residual[o];
        float bb = bias[gc];
        f32x4 st;
#pragma unroll
        for (int r = 0; r < 4; ++r)
          st[r] = acc[m][n][r] * sred[lrow + r] + bb + res[r];
        *(f32x4*)&((float*)Dp)[o] = st;
      }
    }
    return;
  }

  // ---- bf16-storing epilogues (0/1/5): per-wave LDS repack -> coalesced us8 stores
  float* slab = ((float*)(void*)Abuf) + wave * 1088;     // 16 rows x 68 f32 per wave
  const int jt = by;
  unsigned short* Dst = (unsigned short*)Dp + (long)z * Dz;
#pragma unroll
  for (int m = 0; m < 8; ++m) {
    float ps[4] = {0.f, 0.f, 0.f, 0.f};
#pragma unroll
    for (int n = 0; n < NREP; ++n) {
      float bcol = 0.f;
      if constexpr (EPI == 0) bcol = bias[col0 + wn * (NREP * 16) + n * 16 + lr];
#pragma unroll
      for (int r = 0; r < 4; ++r) {
        float v = acc[m][n][r];
        if constexpr (EPI == 0) v += bcol;
        else if constexpr (EPI == 1) v += bias[row0 + wm * 128 + m * 16 + rb + r];
        else if constexpr (EPI == 5) { v = exp2f(v * scale); ps[r] += v; }
        slab[(rb + r) * 68 + n * 16 + lr] = v;
      }
    }
    if constexpr (EPI == 5) {
#pragma unroll
      for (int r = 0; r < 4; ++r) {
        ps[r] += __shfl_xor(ps[r], 1);
        ps[r] += __shfl_xor(ps[r], 2);
        ps[r] += __shfl_xor(ps[r], 4);
        ps[r] += __shfl_xor(ps[r], 8);
      }
      if (lr == 0) {
#pragma unroll
        for (int r = 0; r < 4; ++r)
          rs[((long)z * 1024 + row0 + wm * 128 + m * 16 + rb + r) * 16 + jt * 4 + wn] = ps[r];
      }
    }
    if constexpr (NREP == 4) {
#pragma unroll
      for (int p = 0; p < 2; ++p) {
        int rl = p * 8 + (lane >> 3);
        int c8 = (lane & 7) * 8;
        f32x4 v0 = *(const f32x4*)&slab[rl * 68 + c8];
        f32x4 v1 = *(const f32x4*)&slab[rl * 68 + c8 + 4];
        us8 o;
        o[0] = f2bf(v0.x); o[1] = f2bf(v0.y); o[2] = f2bf(v0.z); o[3] = f2bf(v0.w);
        o[4] = f2bf(v1.x); o[5] = f2bf(v1.y); o[6] = f2bf(v1.z); o[7] = f2bf(v1.w);
        *(us8*)&Dst[(row0 + wm * 128 + m * 16 + rl) * ldd + col0 + wn * 64 + c8] = o;
      }
    } else {
      int rl = lane >> 2;
      int c8 = (lane & 3) * 8;
      f32x4 v0 = *(const f32x4*)&slab[rl * 68 + c8];
      f32x4 v1 = *(const f32x4*)&slab[rl * 68 + c8 + 4];
      us8 o;
      o[0] = f2bf(v0.x); o[1] = f2bf(v0.y); o[2] = f2bf(v0.z); o[3] = f2bf(v0.w);
      o[4] = f2bf(v1.x); o[5] = f2bf(v1.y); o[6] = f2bf(v1.z); o[7] = f2bf(v1.w);
      *(us8*)&Dst[(row0 + wm * 128 + m * 16 + rl) * ldd + col0 + wn * 32 + c8] = o;
    }
  }
}

extern "C" void kernel_launch(void* const* d_in, const int* in_sizes, int n_in,
                              void* d_out, int out_size, void* d_ws, size_t ws_size,
                              hipStream_t stream) {
  const float* x     = (const float*)d_in[0];
  const float* gamma = (const float*)d_in[1];
  const float* beta  = (const float*)d_in[2];
  const float* wq    = (const float*)d_in[3];
  const float* bq    = (const float*)d_in[4];
  const float* wk    = (const float*)d_in[5];
  const float* bk    = (const float*)d_in[6];
  const float* wv    = (const float*)d_in[7];
  const float* bv    = (const float*)d_in[8];
  const float* wo    = (const float*)d_in[9];
  const float* bo    = (const float*)d_in[10];
  float* out = (float*)d_out;

  char* ws = (char*)d_ws;
  unsigned short* ht   = (unsigned short*)(ws + 0);           // [16384,512] bf16
  unsigned short* qkt  = (unsigned short*)(ws + 16777216);    // [16384,1024] bf16 (q | k)
  unsigned short* VWT  = (unsigned short*)(ws + 50331648);    // [512,16384] bf16 (wo.v)
  unsigned short* S    = (unsigned short*)(ws + 83886080);    // [16,1024,1024] bf16 (P unnorm)
  unsigned short* wqkb = (unsigned short*)(ws + 117440512);   // [1024,512] bf16
  unsigned short* wvT  = (unsigned short*)(ws + 119537664);   // [512,512] bf16 (k,c)
  unsigned short* wob  = (unsigned short*)(ws + 120061952);   // [512,512] bf16
  unsigned short* WVO  = (unsigned short*)(ws + 120586240);   // [512,512] bf16
  float* bqk           = (float*)(ws + 121110528);            // [1024] f32
  float* bvo           = (float*)(ws + 121114624);            // [512] f32
  float* stats         = (float*)(ws + 121116672);            // [512,2] f32
  float* rs            = (float*)(ws + 121122816);            // [16,1024,16] f32 partial rowsums

  convert_w<<<1026, 256, 0, stream>>>(wq, wk, wo, bq, bk, bv,
                                      wqkb, wob, bqk, bvo);
  transpose_wv<<<dim3(8, 8), 256, 0, stream>>>(wv, wvT);
  wprod<<<dim3(8, 8), 256, 0, stream>>>(wob, wvT, WVO);
  gn_stats<<<512, 256, 0, stream>>>(x, stats);
  gn_apply<<<dim3(16, 8, 16), 256, 0, stream>>>(x, stats, gamma, beta, ht);

  // G1: qkt[i, j] = sum_c ht[i,c] * wqk[j,c] + bqk[j]      (64x4 = 256 blocks)
  gemm256<4, 0, 0><<<dim3(64, 4, 1), 512, 0, stream>>>(ht, 512, 0, wqkb, 512, 0,
                                                       qkt, 1024, 0, bqk, 0.f, 512, nullptr, nullptr);
  // G2: VWT[o, t] = sum_k WVO[o,k] * ht[t,k] + bvo[o]      (2x128 = 256 blocks)
  gemm256<2, 1, 0><<<dim3(2, 128, 1), 512, 0, stream>>>(WVO, 512, 0, ht, 512, 0,
                                                        VWT, 16384, 0, bvo, 0.f, 512, nullptr, nullptr);
  // G3: P[b,i,j] = exp2(scale' * sum_c q[i,c]*k[j,c]), rowsum partials -> rs  (4x4x16, XCD-swz)
  gemm256<4, 5, 1><<<dim3(4, 4, 16), 512, 0, stream>>>(qkt, 1024, 1048576L, qkt + 512, 1024, 1048576L,
                                                       S, 1024, 1048576L, nullptr,
                                                       0.06375871416f, 512, nullptr, rs);
  // G4: out[b,o,n] = dinv_n * sum_j P[b,n,j] * VWT[o, b*N+j] + bo[o] + x[b,o,n]  (4x4x16, XCD-swz)
  gemm256<2, 7, 1><<<dim3(4, 4, 16), 512, 0, stream>>>(S, 1024, 1048576L,
                                                       VWT, 16384, 1024,
                                                       out, 0, 0, bo, 0.f, 1024, x, rs);
}